// Round 27
// baseline (910.584 us; speedup 1.0000x reference)
//
#include <hip/hip_runtime.h>
#include <math.h>

#define T_DIM 1024
#define B_DIM 256
#define D_DIM 32
#define H_DIM 128
#define HP 68   // float stride between the two 64-float h halves (17 quads)

// Bit-faithful XLA-CPU / Eigen fast-tanh, WITH-FMA variant — FROZEN.
// Verified bit-exact vs the harness reference (absmax 0.0, rounds 15-26).
__device__ __forceinline__ float xla_tanh_fma_f32(float x) {
  const float plim = 7.99881172180175781f;
  float xc = fminf(fmaxf(x, -plim), plim);
  float x2 = __fmul_rn(xc, xc);
  float p;
  p = fmaf(x2, -2.76076847742355e-16f, 2.00018790482477e-13f);
  p = fmaf(x2, p, -8.60467152213735e-11f);
  p = fmaf(x2, p,  5.12229709037114e-08f);
  p = fmaf(x2, p,  1.48572235717979e-05f);
  p = fmaf(x2, p,  6.37261928875436e-04f);
  p = fmaf(x2, p,  4.89352455891786e-03f);
  float num = __fmul_rn(xc, p);
  float q;
  q = fmaf(x2, 1.19825839466702e-06f, 1.18534705686654e-04f);
  q = fmaf(x2, q, 2.26843463243900e-03f);
  q = fmaf(x2, q, 4.89352518554385e-03f);
  float r = __fdiv_rn(num, q);
  return (fabsf(x) < 0.0004f) ? x : r;
}

// Accumulator hop: lane L receives lane L-1 (row_shr:1, exact bit copy).
__device__ __forceinline__ float dpp_shr1(float v) {
  return __int_as_float(__builtin_amdgcn_update_dpp(
      __float_as_int(v), __float_as_int(v), 0x111, 0xf, 0xf, false));
}

// R26 (2-lane systolic, padded h, conflict-free) + TLP: TWO batch rows per
// 512-thread block. Waves 0-3 run row A, waves 4-7 row B — 2 waves/SIMD,
// one per row, so while one row's wave stalls on its serial FMA chain
// (the bit-exact floor), the other row's wave issues. R26 measured 52%
// VALUBusy at 1 wave/SIMD: half the issue slots were dependency gaps.
// Also: s1 (x-dot, register-only) emitted BEFORE s2 in each round so its
// 16 independent FMAs cover the post-barrier LDS h-read latency
// (inter-chain scheduling only — separate accumulators, bits unchanged).
__global__ __launch_bounds__(512, 1) void diffeq_kernel(
    const float* __restrict__ x, const float* __restrict__ state,
    const float* __restrict__ W_in, const float* __restrict__ W_h,
    const float* __restrict__ bias, float* __restrict__ out) {
  __shared__ __align__(16) float hbuf[2][2][2 * HP];  // [row][pingpong][...]

  const int tid = threadIdx.x;          // 0..511
  const int row = tid >> 8;             // 0..1 (wave-aligned: 4 waves each)
  const int lt  = tid & 255;
  const int p   = lt >> 1;              // output index 0..127
  const int i   = lt & 1;               // half 0..1 (pairs lane-aligned)
  const int b   = 2 * blockIdx.x + row; // batch row

  // ---- this lane's weight slices (constant-indexed -> SROA) ----
  float wh[64];
#pragma unroll
  for (int m = 0; m < 64; ++m) wh[m] = W_h[(64 * i + m) * H_DIM + p];
  float wx[16];
#pragma unroll
  for (int m = 0; m < 16; ++m) wx[m] = W_in[(16 * i + m) * H_DIM + p];
  const float bj = bias[p];
  float hown = state[(size_t)b * H_DIM + p];  // true only on lane i==1

  float* h0 = hbuf[row][0];
  float* h1 = hbuf[row][1];
  if (lt < H_DIM)
    h0[HP * (lt >> 6) + (lt & 63)] = state[(size_t)b * H_DIM + lt];

  const size_t out_row = (size_t)b * H_DIM + p;
  const float4* xg4 = reinterpret_cast<const float4*>(x + (size_t)b * D_DIM);
  const int xs4 = B_DIM * D_DIM / 4;    // float4 stride per t

  // x quads double-buffered in named registers (lane needs quads 4i..4i+3).
  float4 xa0, xa1, xa2, xa3, xb0, xb1, xb2, xb3;
  {
    const float4* xp = xg4 + 4 * i;     // t = 0
    xa0 = xp[0]; xa1 = xp[1]; xa2 = xp[2]; xa3 = xp[3];
  }
  __syncthreads();

#define STEP(HRD, HWR, X0, X1, X2, X3, TIDX) { \
    const float4* hb4 = reinterpret_cast<const float4*>(HRD); \
    float s1 = 0.f, s2 = 0.f; \
    _Pragma("unroll") \
    for (int r = 0; r < 2; ++r) { \
      /* s1 chunk first: 16 reg-only FMAs cover this round's LDS latency */ \
      s1 = fmaf(X0.x, wx[0],  s1); s1 = fmaf(X0.y, wx[1],  s1); \
      s1 = fmaf(X0.z, wx[2],  s1); s1 = fmaf(X0.w, wx[3],  s1); \
      s1 = fmaf(X1.x, wx[4],  s1); s1 = fmaf(X1.y, wx[5],  s1); \
      s1 = fmaf(X1.z, wx[6],  s1); s1 = fmaf(X1.w, wx[7],  s1); \
      s1 = fmaf(X2.x, wx[8],  s1); s1 = fmaf(X2.y, wx[9],  s1); \
      s1 = fmaf(X2.z, wx[10], s1); s1 = fmaf(X2.w, wx[11], s1); \
      s1 = fmaf(X3.x, wx[12], s1); s1 = fmaf(X3.y, wx[13], s1); \
      s1 = fmaf(X3.z, wx[14], s1); s1 = fmaf(X3.w, wx[15], s1); \
      _Pragma("unroll") \
      for (int m = 0; m < 16; ++m) { \
        float4 h4 = hb4[17 * i + m];    /* padded: bank-disjoint halves */ \
        s2 = fmaf(h4.x, wh[4 * m + 0], s2); \
        s2 = fmaf(h4.y, wh[4 * m + 1], s2); \
        s2 = fmaf(h4.z, wh[4 * m + 2], s2); \
        s2 = fmaf(h4.w, wh[4 * m + 3], s2); \
      } \
      if (r < 1) { s1 = dpp_shr1(s1); s2 = dpp_shr1(s2); } \
    } \
    float a  = __fadd_rn(__fadd_rn(s1, s2), bj); \
    float th = xla_tanh_fma_f32(a); \
    float hv = __fadd_rn(hown, th); \
    if (i == 1) (HWR)[HP * (p >> 6) + (p & 63)] = hv; \
    hown = hv;  /* only lane 1's is meaningful */ \
    __syncthreads(); \
    if (i == 1) out[(size_t)(TIDX) * (B_DIM * H_DIM) + out_row] = hv; \
  }

  for (int t = 0; t < T_DIM; t += 2) {
    // even step: h0 -> h1, consumes xa; prefetch xb for t+1
    {
      const float4* xp = xg4 + (size_t)(t + 1) * xs4 + 4 * i;
      xb0 = xp[0]; xb1 = xp[1]; xb2 = xp[2]; xb3 = xp[3];
    }
    STEP(h0, h1, xa0, xa1, xa2, xa3, t)
    // odd step: h1 -> h0, consumes xb; prefetch xa for t+2 (clamped)
    {
      int t2 = (t + 2 < T_DIM) ? (t + 2) : (T_DIM - 1);
      const float4* xp = xg4 + (size_t)t2 * xs4 + 4 * i;
      xa0 = xp[0]; xa1 = xp[1]; xa2 = xp[2]; xa3 = xp[3];
    }
    STEP(h1, h0, xb0, xb1, xb2, xb3, t + 1)
  }

  // final_state = h after last step (== outputs[T-1])
  if (i == 1) out[(size_t)T_DIM * B_DIM * H_DIM + out_row] = hown;
}

extern "C" void kernel_launch(void* const* d_in, const int* in_sizes, int n_in,
                              void* d_out, int out_size, void* d_ws, size_t ws_size,
                              hipStream_t stream) {
  const float* x     = (const float*)d_in[0];
  const float* state = (const float*)d_in[1];
  const float* W_in  = (const float*)d_in[2];
  const float* W_h   = (const float*)d_in[3];
  const float* bias  = (const float*)d_in[4];
  float* out = (float*)d_out;

  diffeq_kernel<<<B_DIM / 2, 512, 0, stream>>>(x, state, W_in, W_h, bias, out);
}